// Round 7
// baseline (1001.396 us; speedup 1.0000x reference)
//
#include <hip/hip_runtime.h>
#include <stdint.h>

typedef unsigned short u16;
typedef unsigned char  u8;
typedef unsigned int   u32;
typedef unsigned long long u64;
typedef __attribute__((ext_vector_type(8))) short  short8;
typedef __attribute__((ext_vector_type(4))) float  floatx4;

#define Bz   16
#define Mm   1024
#define Nn   1024
#define Dd   1024
#define HIDh 512
#define INV_SQRT_D 0.03125f
#define NEGINF (-1.0e9f)
#define BMDc  ((size_t)Bz * Mm * Dd)
#define sMDc  ((long)Mm * Dd)

__device__ __forceinline__ float bf2f(u16 h) {
    union { u32 u; float f; } c; c.u = ((u32)h) << 16; return c.f;
}
__device__ __forceinline__ u16 f2bf(float f) {
    union { float f; u32 u; } c; c.f = f;
    u32 u = c.u;
    return (u16)((u + 0x7FFFu + ((u >> 16) & 1u)) >> 16);
}
__device__ __forceinline__ void g2lds16(const u16* g, u16* l) {
    __builtin_amdgcn_global_load_lds((const __attribute__((address_space(1))) void*)g,
                                     (__attribute__((address_space(3))) void*)l, 16, 0, 0);
}

__device__ __forceinline__ float waveSum(float v) {
#pragma unroll
    for (int o = 32; o > 0; o >>= 1) v += __shfl_xor(v, o);
    return v;
}
__device__ __forceinline__ float waveMax(float v) {
#pragma unroll
    for (int o = 32; o > 0; o >>= 1) v = fmaxf(v, __shfl_xor(v, o));
    return v;
}

// ===================== persistent 7-item GEMM: sim (1) + proj (6), 256 blocks =====================
// K-loop schedule byte-equivalent to the verified gemm256 (rounds 2/4/5/6); tiles tt+1/tt+2 past an
// item's end roll into the next item's tiles 0/1 (same buffer parity; pipeline never drains).
// Epilogue: 16 KiB bounce region (separate from staging LDS), raw barriers + lgkmcnt(0) (NOT
// __syncthreads: would vmcnt(0)-drain the in-flight next-item loads). Boundary wait = vmcnt(22)
// = 16 epilogue stores + 6 loads (FIFO counting => same guarantee as the old vmcnt(6)).
struct Item { const u16* A; const u16* B; u16* C; const float* bias; int tr; };

__global__ __launch_bounds__(512, 2) void gemm_fused7(
    const u16* __restrict__ oVb, const u16* __restrict__ oTb,
    const u16* __restrict__ Wc, const float* __restrict__ bcat,
    u16* __restrict__ S3a,
    u16* __restrict__ S0a, u16* __restrict__ S1a, u16* __restrict__ S2a,
    u16* __restrict__ S0b, u16* __restrict__ S1b, u16* __restrict__ S2b)
{
    __shared__ __align__(16) u16 lds[2][2][256 * 64];   // 128 KiB staging (dbuf)
    __shared__ __align__(16) u16 bounce[8192];          // 16 KiB epilogue bounce
    const int tid  = threadIdx.x;
    const int lane = tid & 63;
    const int wv   = tid >> 6;
    const int wr   = wv >> 2;
    const int wc   = wv & 3;
    const int fr   = lane & 15, fq = lane >> 4;
    const int p    = blockIdx.x;                        // 0..255

    const int lrow = lane >> 3;
    const int scol = ((lane & 7) ^ lrow) << 3;
    const int sw   = fr & 7;
    const int kc0  = ((fq ^ sw) << 3);
    const int kc1  = (((4 + fq) ^ sw) << 3);

    // item provider: g=0 sim; g=1..6 proj (z = (g-1)/3, w = (g-1)%3) — round-6 verified mappings
    auto make_item = [&](int g) -> Item {
        Item it;
        if (g == 0) {
            int wg = (p & 7) * 32 + (p >> 3);
            const int bx = wg & 3; wg >>= 2;
            const int by = wg & 3;
            const int bz = wg >> 2;
            it.A = oVb + (size_t)bz * sMDc + (size_t)bx * 256 * 1024;
            it.B = oTb + (size_t)bz * sMDc + (size_t)by * 256 * 1024;
            it.C = S3a + (size_t)bz * ((long)Mm * Nn) + (size_t)bx * 256 * 1024 + by * 256;
            it.bias = nullptr; it.tr = 0;
        } else {
            const int g2 = g - 1, z = g2 / 3, w = g2 % 3;
            const int x = p & 7, l = p >> 3;
            const int x0 = (x & 3) * 16, y0 = (x >> 2) * 6;
            int bx, by;
            if (w == 0)      { bx = x0 + (l & 7);      by = y0 + (l >> 3); }
            else if (w == 1) { bx = x0 + 8 + (l & 7);  by = y0 + (l >> 3); }
            else             { bx = x0 + (l & 15);     by = y0 + 4 + (l >> 4); }
            const long tM = (long)bx * 256, tN = (long)by * 256;
            it.A = (z ? oTb : oVb) + (size_t)tM * 1024;
            it.B = Wc + (size_t)z * 3 * Dd * Dd + (size_t)tN * 1024;
            it.bias = bcat + z * 3072 + tN;
            const int oid = (int)(tN >> 10);
            const long colN = tN & 1023;
            if (oid == 0) {
                it.C = (z ? S0b : S0a) + (size_t)tM * 1024 + colN; it.tr = 0;
            } else if (oid == 1) {
                it.C = (z ? S1a : S1b) + (size_t)tM * 1024 + colN; it.tr = 0;
            } else {
                u16* Pv = z ? S2a : S2b;
                it.C = Pv + (tM >> 10) * sMDc + colN * 1024 + (tM & 1023); it.tr = 1;
            }
        }
        return it;
    };

    Item cur = make_item(0);
    Item nxt = make_item(1);

    floatx4 acc[8][4];
#pragma unroll
    for (int i = 0; i < 8; ++i)
#pragma unroll
        for (int j = 0; j < 4; ++j) acc[i][j] = (floatx4){0.f, 0.f, 0.f, 0.f};

    auto stageI = [&](const Item& it, int tu, int side, int hh, int bb) {
#pragma unroll
        for (int i2 = 0; i2 < 2; ++i2) {
            const int j = i2 * 8 + wv;
            const int prow = side ? (((j >> 2) << 6) + (hh << 5) + ((j & 3) << 3))
                                  : (((j >> 3) << 7) + (hh << 6) + ((j & 7) << 3));
            const u16* src = side ? it.B : it.A;
            g2lds16(src + (size_t)(prow + lrow) * 1024 + (size_t)(tu << 6) + scol,
                    &lds[bb][side][prow * 64]);
        }
    };

    short8 Af[4][2], Bf[4][2];
    auto quad = [&](int mb, int nb) {
#pragma unroll
        for (int m = 0; m < 4; ++m)
#pragma unroll
            for (int n = 0; n < 2; ++n) {
                acc[mb + m][nb + n] = __builtin_amdgcn_mfma_f32_16x16x32_bf16(
                    Af[m][0], Bf[nb + n][0], acc[mb + m][nb + n], 0, 0, 0);
                acc[mb + m][nb + n] = __builtin_amdgcn_mfma_f32_16x16x32_bf16(
                    Af[m][1], Bf[nb + n][1], acc[mb + m][nb + n], 0, 0, 0);
            }
    };

    // epilogue: bf16, optional bias, optional transposed; 8 rounds x 32 rows/cols via bounce
    auto epilogue = [&](const Item& it) {
        float bvj[4];
#pragma unroll
        for (int j = 0; j < 4; ++j)
            bvj[j] = it.bias ? it.bias[(wc << 6) + (j << 4) + fr] : 0.f;
        if (!it.tr) {
#pragma unroll
            for (int k = 0; k < 8; ++k) {
                if (wr == (k >> 2)) {
#pragma unroll
                    for (int ji = 0; ji < 2; ++ji) {
                        const int i = 2 * (k & 3) + ji;
#pragma unroll
                        for (int j = 0; j < 4; ++j) {
                            const int col = (wc << 6) + (j << 4) + fr;
                            const int c = col >> 3;
#pragma unroll
                            for (int r = 0; r < 4; ++r) {
                                const int lr = ((i & 1) << 4) + (fq << 2) + r;
                                bounce[lr * 256 + (((c + lr) & 31) << 3) + (col & 7)] =
                                    f2bf(acc[i][j][r] + bvj[j]);
                            }
                        }
                    }
                }
                asm volatile("s_waitcnt lgkmcnt(0)" ::: "memory");
                __builtin_amdgcn_sched_barrier(0);
                __builtin_amdgcn_s_barrier();
#pragma unroll
                for (int s = 0; s < 2; ++s) {
                    const int u = tid + (s << 9);
                    const int lr = u >> 5, ch = u & 31;
                    const short8 v = *(const short8*)&bounce[lr * 256 + (((ch + lr) & 31) << 3)];
                    *(short8*)&it.C[(size_t)(32 * k + lr) * 1024 + ch * 8] = v;
                }
                __builtin_amdgcn_s_barrier();
            }
        } else {
            char* bc8 = (char*)&bounce[0];
#pragma unroll
            for (int k = 0; k < 8; ++k) {
                if (wc == (k >> 1)) {
#pragma unroll
                    for (int jj = 0; jj < 2; ++jj) {
                        const int j = 2 * (k & 1) + jj;
                        const int lc = (jj << 4) + fr;        // col - 32k
#pragma unroll
                        for (int i = 0; i < 8; ++i) {
                            const int m0 = (wr << 7) + (i << 4) + (fq << 2);
                            const u64 pk = (u64)f2bf(acc[i][j][0] + bvj[j])
                                         | ((u64)f2bf(acc[i][j][1] + bvj[j]) << 16)
                                         | ((u64)f2bf(acc[i][j][2] + bvj[j]) << 32)
                                         | ((u64)f2bf(acc[i][j][3] + bvj[j]) << 48);
                            *(u64*)(bc8 + lc * 512 + ((m0 * 2) ^ ((lc & 7) << 4))) = pk;
                        }
                    }
                }
                asm volatile("s_waitcnt lgkmcnt(0)" ::: "memory");
                __builtin_amdgcn_sched_barrier(0);
                __builtin_amdgcn_s_barrier();
#pragma unroll
                for (int s = 0; s < 2; ++s) {
                    const int u = tid + (s << 9);
                    const int lc = u >> 5, mch = u & 31;
                    const short8 v = *(const short8*)(bc8 + lc * 512 + ((mch * 16) ^ ((lc & 7) << 4)));
                    *(short8*)&it.C[(size_t)(32 * k + lc) * 1024 + mch * 8] = v;
                }
                __builtin_amdgcn_s_barrier();
            }
        }
    };

    // prologue: item0 tile0 fully + tile1 {A-lo, B-hi, A-hi}
    stageI(cur, 0, 0, 0, 0); stageI(cur, 0, 1, 0, 0); stageI(cur, 0, 1, 1, 0); stageI(cur, 0, 0, 1, 0);
    stageI(cur, 1, 0, 0, 1); stageI(cur, 1, 1, 1, 1); stageI(cur, 1, 0, 1, 1);
    asm volatile("s_waitcnt vmcnt(6)" ::: "memory");
    __builtin_amdgcn_s_barrier();

    for (int tt = 0; tt < 112; ++tt) {
        const int cb = tt & 1;
        const int gcur = tt >> 4;
        const u16* lA = &lds[cb][0][0];
        const u16* lB = &lds[cb][1][0];

        auto stg = [&](int u, int side, int hh) {
            if (u < 112) {
                const Item& it = ((u >> 4) == gcur) ? cur : nxt;
                stageI(it, u & 15, side, hh, u & 1);
            }
        };

        // ---- phase 0
#pragma unroll
        for (int m = 0; m < 4; ++m) {
            const int ro = ((wr << 7) + (m << 4) + fr) * 64;
            Af[m][0] = *(const short8*)&lA[ro + kc0];
            Af[m][1] = *(const short8*)&lA[ro + kc1];
        }
#pragma unroll
        for (int n = 0; n < 2; ++n) {
            const int ro = ((wc << 6) + (n << 4) + fr) * 64;
            Bf[n][0] = *(const short8*)&lB[ro + kc0];
            Bf[n][1] = *(const short8*)&lB[ro + kc1];
        }
        stg(tt + 1, 1, 0);
        asm volatile("" ::: "memory");
        __builtin_amdgcn_s_barrier();
        asm volatile("s_waitcnt lgkmcnt(0)" ::: "memory");
        __builtin_amdgcn_sched_barrier(0);
        __builtin_amdgcn_s_setprio(1);
        quad(0, 0);
        __builtin_amdgcn_s_setprio(0);
        asm volatile("" ::: "memory");
        __builtin_amdgcn_s_barrier();

        // ---- phase 1
#pragma unroll
        for (int n = 2; n < 4; ++n) {
            const int ro = ((wc << 6) + (n << 4) + fr) * 64;
            Bf[n][0] = *(const short8*)&lB[ro + kc0];
            Bf[n][1] = *(const short8*)&lB[ro + kc1];
        }
        stg(tt + 2, 0, 0);
        asm volatile("" ::: "memory");
        __builtin_amdgcn_s_barrier();
        asm volatile("s_waitcnt lgkmcnt(0)" ::: "memory");
        __builtin_amdgcn_sched_barrier(0);
        __builtin_amdgcn_s_setprio(1);
        quad(0, 2);
        __builtin_amdgcn_s_setprio(0);
        asm volatile("" ::: "memory");
        __builtin_amdgcn_s_barrier();

        // ---- phase 2
#pragma unroll
        for (int m = 0; m < 4; ++m) {
            const int ro = ((wr << 7) + ((m + 4) << 4) + fr) * 64;
            Af[m][0] = *(const short8*)&lA[ro + kc0];
            Af[m][1] = *(const short8*)&lA[ro + kc1];
        }
        stg(tt + 2, 1, 1);
        asm volatile("" ::: "memory");
        __builtin_amdgcn_s_barrier();
        asm volatile("s_waitcnt lgkmcnt(0)" ::: "memory");
        __builtin_amdgcn_sched_barrier(0);
        __builtin_amdgcn_s_setprio(1);
        quad(4, 2);
        __builtin_amdgcn_s_setprio(0);
        asm volatile("" ::: "memory");
        __builtin_amdgcn_s_barrier();

        // ---- phase 3
        stg(tt + 2, 0, 1);
        asm volatile("" ::: "memory");
        __builtin_amdgcn_s_barrier();
        __builtin_amdgcn_s_setprio(1);
        quad(4, 0);
        __builtin_amdgcn_s_setprio(0);

        if ((tt & 15) == 15) {
            // item boundary: epilogue overlaps next item's in-flight prologue loads
            epilogue(cur);
            cur = nxt;
            if (gcur + 2 < 7) nxt = make_item(gcur + 2);
#pragma unroll
            for (int i = 0; i < 8; ++i)
#pragma unroll
                for (int j = 0; j < 4; ++j) acc[i][j] = (floatx4){0.f, 0.f, 0.f, 0.f};
            if (tt + 1 < 112) asm volatile("s_waitcnt vmcnt(22)" ::: "memory");
            asm volatile("" ::: "memory");
            __builtin_amdgcn_s_barrier();
        } else {
            if (tt + 1 < 112) {
                if (tt + 2 < 112) asm volatile("s_waitcnt vmcnt(6)" ::: "memory");
                else              asm volatile("s_waitcnt vmcnt(0)" ::: "memory");
            }
            asm volatile("" ::: "memory");
            __builtin_amdgcn_s_barrier();
        }
    }
}

// ===================== 256x256 8-phase GEMM (round-6 verified, unchanged) =====================
template <bool OUT_FP32>
__global__ __launch_bounds__(512, 2) void gemm256(
    const u16* __restrict__ Aa, const u16* __restrict__ Ba, void* __restrict__ Ca,
    const u16* __restrict__ Ab, const u16* __restrict__ Bb, void* __restrict__ Cb,
    int K, int ldc, long sA, long sB, long sC)
{
    __shared__ __align__(16) u16 lds[2][2][256 * 64];
    const int tid  = threadIdx.x;
    const int lane = tid & 63;
    const int wv   = tid >> 6;
    const int wr   = wv >> 2;
    const int wc   = wv & 3;
    const int fr   = lane & 15, fq = lane >> 4;

    const int gX = gridDim.x, gY = gridDim.y;
    int bid = blockIdx.x + gX * (blockIdx.y + gY * blockIdx.z);
    const int nwg = gX * gY * gridDim.z;
    int wg = (bid & 7) * (nwg >> 3) + (bid >> 3);
    const int bx = wg % gX; wg /= gX;
    const int by = wg % gY;
    const int bz2 = wg / gY;
    const int br = bz2 >> 4;
    const int bz = bz2 & 15;

    const u16* A  = (br ? Ab : Aa) + (long)bz * sA;
    const u16* Bm = (br ? Bb : Ba) + (long)bz * sB;
    void* Cv = br ? Cb : Ca;

    const long tileM = (long)bx * 256, tileN = (long)by * 256;
    const int T = K >> 6;

    floatx4 acc[8][4];
#pragma unroll
    for (int i = 0; i < 8; ++i)
#pragma unroll
        for (int j = 0; j < 4; ++j) acc[i][j] = (floatx4){0.f, 0.f, 0.f, 0.f};

    const int lrow = lane >> 3;
    const int scol = ((lane & 7) ^ lrow) << 3;
    const int sw   = fr & 7;
    const int kc0  = ((fq ^ sw) << 3);
    const int kc1  = (((4 + fq) ^ sw) << 3);

    auto stage = [&](int tt, int side, int hh, int bb) {
#pragma unroll
        for (int i = 0; i < 2; ++i) {
            const int j = i * 8 + wv;
            const int prow = side ? (((j >> 2) << 6) + (hh << 5) + ((j & 3) << 3))
                                  : (((j >> 3) << 7) + (hh << 6) + ((j & 7) << 3));
            const u16* src = side ? Bm : A;
            const long rb  = side ? tileN : tileM;
            g2lds16(src + (size_t)(rb + prow + lrow) * (size_t)K + (size_t)(tt << 6) + scol,
                    &lds[bb][side][prow * 64]);
        }
    };

    short8 Af[4][2], Bf[4][2];
    auto quad = [&](int mb, int nb) {
#pragma unroll
        for (int m = 0; m < 4; ++m)
#pragma unroll
            for (int n = 0; n < 2; ++n) {
                acc[mb + m][nb + n] = __builtin_amdgcn_mfma_f32_16x16x32_bf16(
                    Af[m][0], Bf[nb + n][0], acc[mb + m][nb + n], 0, 0, 0);
                acc[mb + m][nb + n] = __builtin_amdgcn_mfma_f32_16x16x32_bf16(
                    Af[m][1], Bf[nb + n][1], acc[mb + m][nb + n], 0, 0, 0);
            }
    };

    stage(0, 0, 0, 0); stage(0, 1, 0, 0); stage(0, 1, 1, 0); stage(0, 0, 1, 0);
    stage(1, 0, 0, 1); stage(1, 1, 1, 1); stage(1, 0, 1, 1);
    asm volatile("s_waitcnt vmcnt(6)" ::: "memory");
    __builtin_amdgcn_s_barrier();

    for (int t = 0; t < T; ++t) {
        const int cb = t & 1;
        const u16* lA = &lds[cb][0][0];
        const u16* lB = &lds[cb][1][0];

#pragma unroll
        for (int m = 0; m < 4; ++m) {
            const int ro = ((wr << 7) + (m << 4) + fr) * 64;
            Af[m][0] = *(const short8*)&lA[ro + kc0];
            Af[m][1] = *(const short8*)&lA[ro + kc1];
        }
#pragma unroll
        for (int n = 0; n < 2; ++n) {
            const int ro = ((wc << 6) + (n << 4) + fr) * 64;
            Bf[n][0] = *(const short8*)&lB[ro + kc0];
            Bf[n][1] = *(const short8*)&lB[ro + kc1];
        }
        if (t + 1 < T) stage(t + 1, 1, 0, cb ^ 1);
        asm volatile("" ::: "memory");
        __builtin_amdgcn_s_barrier();
        asm volatile("s_waitcnt lgkmcnt(0)" ::: "memory");
        __builtin_amdgcn_sched_barrier(0);
        __builtin_amdgcn_s_setprio(1);
        quad(0, 0);
        __builtin_amdgcn_s_setprio(0);
        asm volatile("" ::: "memory");
        __builtin_amdgcn_s_barrier();

#pragma unroll
        for (int n = 2; n < 4; ++n) {
            const int ro = ((wc << 6) + (n << 4) + fr) * 64;
            Bf[n][0] = *(const short8*)&lB[ro + kc0];
            Bf[n][1] = *(const short8*)&lB[ro + kc1];
        }
        if (t + 2 < T) stage(t + 2, 0, 0, cb);
        asm volatile("" ::: "memory");
        __builtin_amdgcn_s_barrier();
        asm volatile("s_waitcnt lgkmcnt(0)" ::: "memory");
        __builtin_amdgcn_sched_barrier(0);
        __builtin_amdgcn_s_setprio(1);
        quad(0, 2);
        __builtin_amdgcn_s_setprio(0);
        asm volatile("" ::: "memory");
        __builtin_amdgcn_s_barrier();

#pragma unroll
        for (int m = 0; m < 4; ++m) {
            const int ro = ((wr << 7) + ((m + 4) << 4) + fr) * 64;
            Af[m][0] = *(const short8*)&lA[ro + kc0];
            Af[m][1] = *(const short8*)&lA[ro + kc1];
        }
        if (t + 2 < T) stage(t + 2, 1, 1, cb);
        asm volatile("" ::: "memory");
        __builtin_amdgcn_s_barrier();
        asm volatile("s_waitcnt lgkmcnt(0)" ::: "memory");
        __builtin_amdgcn_sched_barrier(0);
        __builtin_amdgcn_s_setprio(1);
        quad(4, 2);
        __builtin_amdgcn_s_setprio(0);
        asm volatile("" ::: "memory");
        __builtin_amdgcn_s_barrier();

        if (t + 2 < T) stage(t + 2, 0, 1, cb);
        asm volatile("" ::: "memory");
        __builtin_amdgcn_s_barrier();
        __builtin_amdgcn_s_setprio(1);
        quad(4, 0);
        __builtin_amdgcn_s_setprio(0);
        if (t + 1 < T) {
            if (t + 2 < T) asm volatile("s_waitcnt vmcnt(6)" ::: "memory");
            else           asm volatile("s_waitcnt vmcnt(0)" ::: "memory");
        }
        asm volatile("" ::: "memory");
        __builtin_amdgcn_s_barrier();
    }

    __syncthreads();
    if constexpr (!OUT_FP32) {
        u16* l2 = (u16*)&lds[0][0][0];
#pragma unroll
        for (int j = 0; j < 4; ++j) {
            const int col = (wc << 6) + (j << 4) + fr;
            const int c   = col >> 3;
#pragma unroll
            for (int i = 0; i < 8; ++i) {
                const int row0 = (wr << 7) + (i << 4) + (fq << 2);
#pragma unroll
                for (int r = 0; r < 4; ++r) {
                    const int row = row0 + r;
                    l2[row * 256 + (((c + row) & 31) << 3) + (col & 7)] = f2bf(acc[i][j][r]);
                }
            }
        }
        __syncthreads();
        u16* C = (u16*)Cv + (long)bz * sC;
#pragma unroll
        for (int it = 0; it < 16; ++it) {
            const int row = it * 16 + (tid >> 5);
            const int ch  = tid & 31;
            const short8 v = *(const short8*)&l2[row * 256 + (((ch + row) & 31) << 3)];
            *(short8*)&C[(tileM + row) * (long)ldc + tileN + ch * 8] = v;
        }
    } else {
        float* l2f = (float*)&lds[0][0][0];
        float* C = (float*)Cv + (long)bz * sC;
#pragma unroll
        for (int pass = 0; pass < 2; ++pass) {
            if (pass) __syncthreads();
            if (wr == pass) {
#pragma unroll
                for (int j = 0; j < 4; ++j) {
                    const int col = (wc << 6) + (j << 4) + fr;
                    const int c   = col >> 2;
#pragma unroll
                    for (int i = 0; i < 8; ++i) {
                        const int row0 = (i << 4) + (fq << 2);
#pragma unroll
                        for (int r = 0; r < 4; ++r)
                            l2f[(row0 + r) * 256 + (((c + (fq << 2)) & 63) << 2) + (col & 3)] = acc[i][j][r];
                    }
                }
            }
            __syncthreads();
#pragma unroll
            for (int it = 0; it < 16; ++it) {
                const int row = it * 8 + (tid >> 6);
                const int ch  = tid & 63;
                const int rot = (row >> 2) & 3;
                const float4 v = *(const float4*)&l2f[row * 256 + (((ch + (rot << 2)) & 63) << 2)];
                *(float4*)&C[(tileM + pass * 128 + row) * (long)ldc + tileN + ch * 4] = v;
            }
        }
    }
}

// ---------------- fused fp32->bf16 conversion + column-mean pooling ----------------
__global__ __launch_bounds__(256) void conv_pool(
    const float* __restrict__ oV, const float* __restrict__ oT,
    u16* __restrict__ oVb, u16* __restrict__ oTb,
    float* __restrict__ vpool, float* __restrict__ tpool)
{
    const int b = blockIdx.y, srci = blockIdx.z;
    const float* src = (srci ? oT : oV) + (size_t)b * Mm * Dd;
    u16* dst = (srci ? oTb : oVb) + (size_t)b * Mm * Dd;
    const int c4 = threadIdx.x * 4;
    const int r0 = blockIdx.x * 64;
    float4 s = {0.f, 0.f, 0.f, 0.f};
    for (int r = r0; r < r0 + 64; ++r) {
        const float4 v = *(const float4*)&src[(size_t)r * Dd + c4];
        s.x += v.x; s.y += v.y; s.z += v.z; s.w += v.w;
        ushort4 o;
        o.x = f2bf(v.x); o.y = f2bf(v.y); o.z = f2bf(v.z); o.w = f2bf(v.w);
        *(ushort4*)&dst[(size_t)r * Dd + c4] = o;
    }
    float* pool = (srci ? tpool : vpool) + (size_t)b * Dd + c4;
    atomicAdd(pool + 0, s.x * (1.0f / Mm));
    atomicAdd(pool + 1, s.y * (1.0f / Mm));
    atomicAdd(pool + 2, s.z * (1.0f / Mm));
    atomicAdd(pool + 3, s.w * (1.0f / Mm));
}

// ---------------- 6x weight fp32 -> bf16 ----------------
__global__ __launch_bounds__(256) void wconv6(
    const float* __restrict__ w0, const float* __restrict__ w1, const float* __restrict__ w2,
    const float* __restrict__ w3, const float* __restrict__ w4, const float* __restrict__ w5,
    u16* __restrict__ dst)
{
    const float* src;
    switch (blockIdx.y) {
        case 0: src = w0; break; case 1: src = w1; break; case 2: src = w2; break;
        case 3: src = w3; break; case 4: src = w4; break; default: src = w5; break;
    }
    const size_t i = (size_t)blockIdx.x * 256 + threadIdx.x;
    const float4 a = ((const float4*)src)[2 * i];
    const float4 b = ((const float4*)src)[2 * i + 1];
    short8 o;
    o[0]=(short)f2bf(a.x); o[1]=(short)f2bf(a.y); o[2]=(short)f2bf(a.z); o[3]=(short)f2bf(a.w);
    o[4]=(short)f2bf(b.x); o[5]=(short)f2bf(b.y); o[6]=(short)f2bf(b.z); o[7]=(short)f2bf(b.w);
    *(short8*)(dst + (((size_t)blockIdx.y) << 20) + 8 * i) = o;
}

// ---------------- concat 6 bias vectors ----------------
__global__ __launch_bounds__(256) void bcat_kernel(
    const float* __restrict__ b0, const float* __restrict__ b1, const float* __restrict__ b2,
    const float* __restrict__ b3, const float* __restrict__ b4, const float* __restrict__ b5,
    float* __restrict__ out)
{
    const int i = blockIdx.x * 256 + threadIdx.x;
    const int seg = i >> 10;
    const float* s;
    switch (seg) {
        case 0: s = b0; break; case 1: s = b1; break; case 2: s = b2; break;
        case 3: s = b3; break; case 4: s = b4; break; default: s = b5; break;
    }
    out[i] = s[i & 1023];
}

// ---------------- FFN ----------------
__global__ __launch_bounds__(256) void ffn1_kernel(
    const float* __restrict__ vpool, const float* __restrict__ tpool,
    const float* __restrict__ f1w, const float* __restrict__ f1b,
    float* __restrict__ hbuf)
{
    const int j = blockIdx.x, b = blockIdx.y;
    const int t = threadIdx.x, wv = t >> 6, lane = t & 63;
    __shared__ float red[4];
    const float* w = f1w + (size_t)j * (2 * Dd);
    float a = 0.f;
    for (int k = t; k < Dd; k += 256) a += vpool[b * Dd + k] * w[k];
    for (int k = t; k < Dd; k += 256) a += tpool[b * Dd + k] * w[Dd + k];
    a = waveSum(a);
    if (lane == 0) red[wv] = a;
    __syncthreads();
    if (t == 0) hbuf[b * HIDh + j] = fmaxf(red[0] + red[1] + red[2] + red[3] + f1b[j], 0.0f);
}

__global__ __launch_bounds__(256) void ffn2_kernel(
    const float* __restrict__ hbuf, const float* __restrict__ f2w,
    const float* __restrict__ f2b, float* __restrict__ lbuf)
{
    const int b = blockIdx.x;
    const int t = threadIdx.x, wv = t >> 6, lane = t & 63;
    __shared__ float red[4];
    float p = 0.f;
    for (int j = t; j < HIDh; j += 256) p += hbuf[b * HIDh + j] * f2w[j];
    p = waveSum(p);
    if (lane == 0) red[wv] = p;
    __syncthreads();
    if (t == 0) {
        const float z = red[0] + red[1] + red[2] + red[3] + f2b[0];
        lbuf[b] = 1.0f / (1.0f + expf(-z));
    }
}

// ---------------- sim softmax -> fp32 mask (d_out) + u8 row-major mask ----------------
__global__ __launch_bounds__(256) void sim_softmax_mask(
    const u16* __restrict__ scores, const float* __restrict__ lbuf,
    float* __restrict__ maskF, u8* __restrict__ maskR)
{
    const int row = blockIdx.x, b = blockIdx.y;
    const int t = threadIdx.x, wv = t >> 6, lane = t & 63;
    __shared__ float red[8];
    const size_t off = ((size_t)b * Mm + row) * Nn;
    const uint2 sv = *(const uint2*)(scores + off + 4 * t);
    const float x0 = bf2f((u16)(sv.x & 0xFFFFu)) * INV_SQRT_D;
    const float x1 = bf2f((u16)(sv.x >> 16))     * INV_SQRT_D;
    const float x2 = bf2f((u16)(sv.y & 0xFFFFu)) * INV_SQRT_D;
    const float x3 = bf2f((u16)(sv.y >> 16))     * INV_SQRT_D;
    float mx = waveMax(fmaxf(fmaxf(x0, x1), fmaxf(x2, x3)));
    if (lane == 0) red[wv] = mx;
    __syncthreads();
    mx = fmaxf(fmaxf(red[0], red[1]), fmaxf(red[2], red[3]));
    const float e0 = expf(x0 - mx), e1 = expf(x1 - mx), e2 = expf(x2 - mx), e3 = expf(x3 - mx);
    float s = waveSum(e0 + e1 + e2 + e3);
    if (lane == 0) red[4 + wv] = s;
    __syncthreads();
    const float inv = 1.0f / fmaxf(red[4] + red[5] + red[6] + red[7], 1e-30f);
    const float l = lbuf[b];
    float4 mk;
    mk.x = (e0 * inv >= l) ? 1.0f : 0.0f;
    mk.y = (e1 * inv >= l) ? 1.0f : 0.0f;
    mk.z = (e2 * inv >= l) ? 1.0f : 0.0f;
    mk.w = (e3 * inv >= l) ? 1.0f : 0.0f;
    *(float4*)(maskF + off + 4 * t) = mk;
    const u32 u8mk = (mk.x != 0.f ? 1u : 0u) | (mk.y != 0.f ? 0x100u : 0u)
                   | (mk.z != 0.f ? 0x10000u : 0u) | (mk.w != 0.f ? 0x1000000u : 0u);
    *(u32*)(maskR + off + 4 * t) = u8mk;
}

// ---------------- mask transpose: u8 maskR -> u8 maskT ----------------
__global__ __launch_bounds__(256) void transpose_mask(
    const u8* __restrict__ maskR, u8* __restrict__ maskT)
{
    __shared__ u8 tile[64][68];
    const int m0 = blockIdx.x * 64, n0 = blockIdx.y * 64, b = blockIdx.z;
    const int t = threadIdx.x;
    const int r = t >> 2, c = (t & 3) * 16;
    const uint4 src = *(const uint4*)(maskR + ((size_t)b * Mm + (m0 + r)) * Nn + n0 + c);
    *(uint4*)&tile[r][c] = src;
    __syncthreads();
    union { u8 b[16]; uint4 v; } pk;
#pragma unroll
    for (int k = 0; k < 16; ++k) pk.b[k] = tile[c + k][r];
    *(uint4*)(maskT + ((size_t)b * Nn + (n0 + r)) * Mm + m0 + c) = pk.v;
}

// ---------------- merged masked softmax (both branches), IN-PLACE bf16 ----------------
__global__ __launch_bounds__(256) void masked_softmax2(
    u16* __restrict__ Sa, u16* __restrict__ Sb,
    const u8* __restrict__ mR, const u8* __restrict__ mT)
{
    const int row = blockIdx.x, bb = blockIdx.y;
    const int br = bb >> 4, b = bb & 15;
    u16* scores = br ? Sb : Sa;
    const u8* mask = br ? mT : mR;
    const int t = threadIdx.x, wv = t >> 6, lane = t & 63;
    __shared__ float red[8];
    const size_t off = ((size_t)b * Mm + row) * Nn;
    const uint2 sv = *(const uint2*)(scores + off + 4 * t);
    float x0 = bf2f((u16)(sv.x & 0xFFFFu)) * INV_SQRT_D;
    float x1 = bf2f((u16)(sv.x >> 16))     * INV_SQRT_D;
    float x2 = bf2f((u16)(sv.y & 0xFFFFu)) * INV_SQRT_D;
    float x3 = bf2f((u16)(sv.y >> 16))     * INV_SQRT_D;
    const u32 mk = *(const u32*)(mask + off + 4 * t);
    if (!(mk & 0x000000FFu)) x0 = NEGINF;
    if (!(mk & 0x0000FF00u)) x1 = NEGINF;
    if (!(mk & 0x00FF0000u)) x2 = NEGINF;
    if (!(mk & 0xFF000000u)) x3 = NEGINF;
    float mx = waveMax(fmaxf(fmaxf(x0, x1), fmaxf(x2, x3)));
    if (lane == 0) red[wv] = mx;
    __syncthreads();
    mx = fmaxf(fmaxf(red[0], red[1]), fmaxf(red[2], red[3]));
    const float e0 = expf(x0 - mx), e1 = expf(x1 - mx), e2 = expf(x2 - mx), e3 = expf(x3 - mx);
    float s = waveSum(e0 + e1 + e2 + e3);
    if (lane == 0) red[4 + wv] = s;
    __syncthreads();
    const float inv = 1.0f / fmaxf(red[4] + red[5] + red[6] + red[7], 1e-30f);
    uint2 pk;
    pk.x = (u32)f2bf(e0 * inv) | ((u32)f2bf(e1 * inv) << 16);
    pk.y = (u32)f2bf(e2 * inv) | ((u32)f2bf(e3 * inv) << 16);
    *(uint2*)(scores + off + 4 * t) = pk;
}

extern "C" void kernel_launch(void* const* d_in, const int* in_sizes, int n_in,
                              void* d_out, int out_size, void* d_ws, size_t ws_size,
                              hipStream_t stream)
{
    (void)in_sizes; (void)n_in; (void)out_size; (void)ws_size;
    const float* oV     = (const float*)d_in[0];
    const float* oT     = (const float*)d_in[1];
    const float* Wq_v_w = (const float*)d_in[2];
    const float* Wq_v_b = (const float*)d_in[3];
    const float* Wk_t_w = (const float*)d_in[4];
    const float* Wk_t_b = (const float*)d_in[5];
    const float* Wv_t_w = (const float*)d_in[6];
    const float* Wv_t_b = (const float*)d_in[7];
    const float* Wq_t_w = (const float*)d_in[8];
    const float* Wq_t_b = (const float*)d_in[9];
    const float* Wk_v_w = (const float*)d_in[10];
    const float* Wk_v_b = (const float*)d_in[11];
    const float* Wv_v_w = (const float*)d_in[12];
    const float* Wv_v_b = (const float*)d_in[13];
    const float* f1w    = (const float*)d_in[14];
    const float* f1b    = (const float*)d_in[15];
    const float* f2w    = (const float*)d_in[16];
    const float* f2b    = (const float*)d_in[17];

    float* out_vt = (float*)d_out;
    float* out_tv = out_vt + BMDc;
    float* maskF  = out_vt + 2 * BMDc;

    u16* S0a = (u16*)d_ws;
    u16* S1a = S0a + BMDc;
    u16* S2a = S1a + BMDc;
    u16* S0b = S2a + BMDc;
    u16* S1b = S0b + BMDc;
    u16* S2b = S1b + BMDc;
    u16* S3a = S2b + BMDc;
    u16* S3b = S3a + BMDc;
    u16* oVb = S3b + BMDc;
    u16* oTb = oVb + BMDc;
    u16* Wc  = oTb + BMDc;
    u8*  maskT = (u8*)(Wc + 6 * (1 << 20));
    u8*  maskR = maskT + BMDc;
    float* bcat  = (float*)(maskR + BMDc);
    float* vpool = bcat + 6144;
    float* tpool = vpool + Bz * Dd;
    float* hbuf  = tpool + Bz * Dd;
    float* lbuf  = hbuf + Bz * HIDh;

    const dim3 blk(256), blk512(512);
    const dim3 gBat2(Mm / 256, Nn / 256, 2 * Bz);       // 512 wg (merged branches)
    const dim3 gRow2(Mm, 2 * Bz);
    const dim3 gTrp(Mm / 64, Nn / 64, Bz);
    const long sMD = sMDc, sMN = (long)Mm * Nn;

    // 0: weights + biases to bf16/concat
    wconv6<<<dim3(512, 6), blk, 0, stream>>>(Wq_v_w, Wk_v_w, Wv_v_w, Wq_t_w, Wk_t_w, Wv_t_w, Wc);
    bcat_kernel<<<dim3(24), blk, 0, stream>>>(Wq_v_b, Wk_v_b, Wv_v_b, Wq_t_b, Wk_t_b, Wv_t_b, bcat);

    // 1: fused convert + pool -> FFN threshold
    hipMemsetAsync(vpool, 0, 2 * Bz * Dd * sizeof(float), stream);
    conv_pool<<<dim3(16, Bz, 2), blk, 0, stream>>>(oV, oT, oVb, oTb, vpool, tpool);
    ffn1_kernel<<<dim3(HIDh, Bz), blk, 0, stream>>>(vpool, tpool, f1w, f1b, hbuf);
    ffn2_kernel<<<dim3(Bz), blk, 0, stream>>>(hbuf, f2w, f2b, lbuf);

    // 2: persistent fused GEMM: sim scores (S3a) + all 6 projections
    gemm_fused7<<<dim3(256), blk512, 0, stream>>>(oVb, oTb, Wc, bcat, S3a,
                                                  S0a, S1a, S2a, S0b, S1b, S2b);

    // 3: masks from sim scores
    sim_softmax_mask<<<dim3(Mm, Bz), blk, 0, stream>>>(S3a, lbuf, maskF, maskR);
    transpose_mask<<<gTrp, blk, 0, stream>>>(maskR, maskT);

    // 4: merged score GEMM (V->T and T->V)
    gemm256<false><<<gBat2, blk512, 0, stream>>>(S0a, S1a, S3a, S0b, S1b, S3b, Dd, Nn, sMD, sMD, sMN);

    // 5: merged masked softmax
    masked_softmax2<<<gRow2, blk, 0, stream>>>(S3a, S3b, maskR, maskT);

    // 6: merged PV GEMM
    gemm256<true><<<gBat2, blk512, 0, stream>>>(S3a, S2a, out_vt, S3b, S2b, out_tv, Nn, Dd, sMN, sMD, sMD);
}